// Round 7
// baseline (85.785 us; speedup 1.0000x reference)
//
#include <hip/hip_runtime.h>

// CharRNN GRU: B=4096, T=256, V=256, H=20, L=15, reset_after=True, drop_rate=0.
// f32 in / f32 out. 3 batches per wave (20 lanes each), no block barriers in
// the recurrence. Recurrent dot in bf16 via v_dot2_f32_bf16 (f32 accum):
// U packed as 30 u32 VGPRs, h exchanged through LDS as bf16 (ds_write_b16 +
// b128/b128/b64 reads, in-order per-wave DS pipeline, lgkmcnt(0) in asm).
// Register footprint ~95 < 128 so U stays resident at 2 waves/EU.

#define BB 4096
#define TT 256
#define VV 256
#define HH 20
#define G3 60    // 3*H
#define LL 15
#define NBATCH 12             // batches per block (4 waves x 3)
#define NTHREADS 256
#define HSTRIDE 24            // u16 per batch slot (48 B, 16B-aligned)

typedef int v4i __attribute__((ext_vector_type(4)));
typedef int v2i __attribute__((ext_vector_type(2)));

__device__ __forceinline__ unsigned short f2bf(float f) {
    union { float f; unsigned int i; } c;
    c.f = f;
    unsigned int x = c.i;
    return (unsigned short)((x + 0x7FFFu + ((x >> 16) & 1u)) >> 16); // RNE
}

__device__ __forceinline__ unsigned pack2bf(float a, float b) {
    return (unsigned)f2bf(a) | ((unsigned)f2bf(b) << 16);
}

__device__ __forceinline__ float fast_rcp(float x) {
#if __has_builtin(__builtin_amdgcn_rcpf)
    return __builtin_amdgcn_rcpf(x);
#else
    return 1.0f / x;
#endif
}

__device__ __forceinline__ float fast_sigmoid(float x) {
    return fast_rcp(1.0f + __expf(-x));
}

__device__ __forceinline__ float fast_tanh(float x) {
    return 1.0f - 2.0f * fast_rcp(1.0f + __expf(2.0f * x));
}

// D = a.x*b.x + a.y*b.y + c  (bf16 inputs packed in u32, f32 accumulate)
__device__ __forceinline__ float dot2bf(unsigned a, unsigned b, float c) {
    float d;
    asm("v_dot2_f32_bf16 %0, %1, %2, %3" : "=v"(d) : "v"(a), "v"(b), "v"(c));
    return d;
}

// one GRU-step h exchange: write my bf16 h, read my group's 20 bf16 h values
// as 10 packed u32. Per-wave DS ops complete in order.
__device__ __forceinline__ void h_exchange(unsigned waddr, unsigned hbf,
                                           unsigned raddr,
                                           v4i& p0, v4i& p1, v2i& p2) {
    asm volatile(
        "ds_write_b16 %3, %4\n\t"
        "ds_read_b128 %0, %5\n\t"
        "ds_read_b128 %1, %5 offset:16\n\t"
        "ds_read_b64 %2, %5 offset:32\n\t"
        "s_waitcnt lgkmcnt(0)"
        : "=&v"(p0), "=&v"(p1), "=&v"(p2)
        : "v"(waddr), "v"(hbf), "v"(raddr));
}

__global__ __launch_bounds__(NTHREADS, 1) void gru_kernel(
    const int* __restrict__ x,            // [B][T] int32
    const float* __restrict__ kernelW,    // [V][3H] f32
    const float* __restrict__ rkernel,    // [H][3H] f32
    const float* __restrict__ bias,       // [2][3H] f32
    const float* __restrict__ dense_w,    // [H][L] f32
    const float* __restrict__ dense_b,    // [L] f32
    float* __restrict__ out)              // [B][L] f32
{
    __shared__ int2  xwall[VV * HH];      // {bf16(z)|bf16(r)<<16, f32 h}: 40960 B
    __shared__ float u_lds[HH * G3];      // staging only (packed into VGPRs)
    __shared__ float w_lds[HH * LL];
    __shared__ float db_lds[LL];
    __shared__ int   x_lds[NBATCH][TT + 1];            // +1 pad
    __shared__ unsigned short hbuf[NBATCH * HSTRIDE + 40]; // bf16 h + scratch

    const int tid = threadIdx.x;
    const long b0 = (long)blockIdx.x * NBATCH;

    // ---- staging (one barrier total) ----
    for (int idx = tid; idx < VV * HH; idx += NTHREADS) {
        const int v = idx / HH, j = idx - v * HH;
        const float vz = kernelW[v * G3 + j]          + bias[j];
        const float vr = kernelW[v * G3 + HH + j]     + bias[HH + j];
        const float vh = kernelW[v * G3 + 2 * HH + j] + bias[2 * HH + j];
        int2 pk;
        pk.x = (int)pack2bf(vz, vr);
        pk.y = __float_as_int(vh);
        xwall[idx] = pk;
    }
    for (int idx = tid; idx < HH * G3; idx += NTHREADS) u_lds[idx] = rkernel[idx];
    for (int idx = tid; idx < HH * LL; idx += NTHREADS) w_lds[idx] = dense_w[idx];
    if (tid < LL) db_lds[tid] = dense_b[tid];
    for (int k = tid; k < NBATCH * TT; k += NTHREADS) {
        const long gi = b0 * TT + k;
        x_lds[k >> 8][k & 255] = (gi < (long)BB * TT) ? x[gi] : 0;
    }
    for (int idx = tid; idx < NBATCH * HSTRIDE + 40; idx += NTHREADS)
        hbuf[idx] = 0;   // h(0) = 0 (bf16 zero)
    __syncthreads();   // the ONLY block barrier

    const int lane = tid & 63;
    const int g3   = lane / 20;            // 0..2 active, 3 for idle lanes 60-63
    const int j    = lane - g3 * 20;
    const bool active = (lane < 60);
    const int lb   = (tid >> 6) * 3 + g3;  // local batch
    const int lbc  = active ? lb : 0;

    const unsigned hbase = (unsigned)(size_t)&hbuf[0];   // LDS byte offset
    const unsigned waddr = active
        ? hbase + 2u * (unsigned)(lb * HSTRIDE + j)
        : hbase + 2u * (unsigned)(NBATCH * HSTRIDE + (tid >> 6) * 8 + (lane - 60));
    const unsigned raddr = hbase + 2u * (unsigned)(HSTRIDE * lbc);

    // recurrent kernel columns j, H+j, 2H+j packed bf16 over i-pairs (30 VGPRs)
    unsigned Uz[10], Ur[10], Uh[10];
    #pragma unroll
    for (int q = 0; q < 10; ++q) {
        Uz[q] = pack2bf(u_lds[(2*q) * G3 + j],        u_lds[(2*q+1) * G3 + j]);
        Ur[q] = pack2bf(u_lds[(2*q) * G3 + HH + j],   u_lds[(2*q+1) * G3 + HH + j]);
        Uh[q] = pack2bf(u_lds[(2*q) * G3 + 2*HH + j], u_lds[(2*q+1) * G3 + 2*HH + j]);
    }
    // pin: forbid re-materialization from LDS inside the loop (fits budget now)
    #pragma unroll
    for (int q = 0; q < 10; ++q)
        asm volatile("" : "+v"(Uz[q]), "+v"(Ur[q]), "+v"(Uh[q]));

    const float brz = bias[G3 + j];
    const float brr = bias[G3 + HH + j];
    const float brh = bias[G3 + 2 * HH + j];

    float hmine = 0.0f;
    unsigned hbf = 0;                      // bf16(hmine) in low 16
    const int* xrow = x_lds[lbc];

    #pragma unroll 2
    for (int t = 0; t < TT; ++t) {
        // exchange h(t): write mine (bf16), read group's 10 packed pairs
        v4i p0, p1; v2i p2;
        h_exchange(waddr, hbf, raddr, p0, p1, p2);
        const unsigned hp[10] = { (unsigned)p0.x, (unsigned)p0.y, (unsigned)p0.z,
                                  (unsigned)p0.w, (unsigned)p1.x, (unsigned)p1.y,
                                  (unsigned)p1.z, (unsigned)p1.w, (unsigned)p2.x,
                                  (unsigned)p2.y };

        const int xv = xrow[t];                      // 3 addrs/wave, broadcast
        const int2 w = xwall[xv * HH + j];           // one ds_read_b64
        const float xz = __uint_as_float(((unsigned)w.x) << 16);
        const float xr = __uint_as_float(((unsigned)w.x) & 0xffff0000u);
        const float xh = __int_as_float(w.y);

        // two dot2 chains per gate (5 deep each)
        float za = brz, ra = brr, ha = brh;
        float zb = 0.f, rb = 0.f, hb = 0.f;
        #pragma unroll
        for (int q = 0; q < 5; ++q) {
            za = dot2bf(hp[q], Uz[q], za);
            ra = dot2bf(hp[q], Ur[q], ra);
            ha = dot2bf(hp[q], Uh[q], ha);
        }
        #pragma unroll
        for (int q = 5; q < 10; ++q) {
            zb = dot2bf(hp[q], Uz[q], zb);
            rb = dot2bf(hp[q], Ur[q], rb);
            hb = dot2bf(hp[q], Uh[q], hb);
        }
        const float z  = fast_sigmoid(xz + (za + zb));
        const float r  = fast_sigmoid(xr + (ra + rb));
        const float hc = fast_tanh(fmaf(r, ha + hb, xh));
        hmine = hc + z * (hmine - hc);
        // one-instruction f32->bf16 (RNE) for next step's exchange
        asm("v_cvt_pk_bf16_f32 %0, %1, %2" : "=v"(hbf) : "v"(hmine), "v"(hmine));
    }

    // final exchange to collect h(T) (bf16) for the dense head
    v4i p0, p1; v2i p2;
    h_exchange(waddr, hbf, raddr, p0, p1, p2);
    const unsigned fp[10] = { (unsigned)p0.x, (unsigned)p0.y, (unsigned)p0.z,
                              (unsigned)p0.w, (unsigned)p1.x, (unsigned)p1.y,
                              (unsigned)p1.z, (unsigned)p1.w, (unsigned)p2.x,
                              (unsigned)p2.y };
    float hf[HH];
    #pragma unroll
    for (int q = 0; q < 10; ++q) {
        hf[2*q]   = __uint_as_float(fp[q] << 16);
        hf[2*q+1] = __uint_as_float(fp[q] & 0xffff0000u);
    }

    // ---- dense head: logits[b][l] = db[l] + sum_i h[i] * W[i][l] ----
    const long gb = b0 + lb;
    if (active && j < LL && gb < BB) {
        float acc = db_lds[j];
        #pragma unroll
        for (int i = 0; i < HH; ++i)
            acc = fmaf(hf[i], w_lds[i * LL + j], acc);
        out[gb * LL + j] = acc;
    }
}

extern "C" void kernel_launch(void* const* d_in, const int* in_sizes, int n_in,
                              void* d_out, int out_size, void* d_ws, size_t ws_size,
                              hipStream_t stream) {
    const int* x            = (const int*)d_in[0];
    // d_in[1] = drop_rate (0.0f) -> dropout is identity; ignored.
    const float* kernelW    = (const float*)d_in[2];
    const float* rkernel    = (const float*)d_in[3];
    const float* bias       = (const float*)d_in[4];
    const float* dense_w    = (const float*)d_in[5];
    const float* dense_b    = (const float*)d_in[6];
    float* out              = (float*)d_out;

    dim3 grid((BB + NBATCH - 1) / NBATCH);   // 342 blocks
    dim3 block(NTHREADS);                    // 256 threads = 4 waves = 12 batches
    gru_kernel<<<grid, block, 0, stream>>>(x, kernelW, rkernel, bias,
                                           dense_w, dense_b, out);
}